// Round 1
// baseline (1104.426 us; speedup 1.0000x reference)
//
#include <hip/hip_runtime.h>
#include <math.h>

// Problem constants (from reference setup_inputs): B=16, C=1, H=1024, W=1024
#define IMG_H 1024
#define IMG_W 1024
#define NB    16
#define NROWS (NB * IMG_H)        // 16384 flat rows
#define WPR   (IMG_W / 32)        // 32 u32 words per row
#define NTOTAL 16777216.0

struct Acc {
    double sE, sB, sT;            // bce partial sums per class
    unsigned int cMask, cEdge;    // counts of label==1 and edge==1
};

// ---------------- Kernel 1: bitpack label + horizontal 15-tap OR dilation ---
// Each block: 8 consecutive flat rows (8192 pixels), 256 threads.
__global__ void k_dilate_h(const int* __restrict__ label,
                           unsigned int* __restrict__ maskbits,
                           unsigned int* __restrict__ rowor) {
    __shared__ unsigned int lm[256];          // 8 rows * 32 words
    const int t = threadIdx.x;
    const int wave = t >> 6, lane = t & 63;
    const long rowBase = (long)blockIdx.x * 8;
    const long pixBase = rowBase * IMG_W;

    #pragma unroll 4
    for (int it = 0; it < 32; ++it) {
        int idx = it * 256 + t;               // 0..8191 within block tile
        int lab = label[pixBase + idx];
        unsigned long long bal = __ballot(lab != 0);
        if (lane == 0) {
            int wi = (it * 256 + wave * 64) >> 5;
            lm[wi]     = (unsigned int)bal;
            lm[wi + 1] = (unsigned int)(bal >> 32);
        }
    }
    __syncthreads();

    // One output word per thread: OR of bits within +/-7 of each bit position.
    const int wd = t & 31;
    unsigned int prev = wd        ? lm[t - 1] : 0u;
    unsigned int cur  =             lm[t];
    unsigned int next = (wd < 31) ? lm[t + 1] : 0u;
    // 64-bit window = bits 16..79 of the 96-bit (prev,cur,next) row segment
    unsigned long long Wn = (((unsigned long long)prev) >> 16)
                          | (((unsigned long long)cur)  << 16)
                          | (((unsigned long long)next) << 48);
    unsigned long long acc = Wn;
    #pragma unroll
    for (int d = 1; d <= 7; ++d) acc |= (Wn >> d) | (Wn << d);

    long o = rowBase * WPR + t;               // coalesced word writes
    maskbits[o] = cur;
    rowor[o]    = (unsigned int)(acc >> 16);
}

// ---------------- Kernel 2: vertical OR + classified BCE + reduction --------
// One block per flat row, 256 threads, 4 pixels/thread (coalesced).
__global__ void k_bce(const float* __restrict__ pred,
                      const unsigned int* __restrict__ maskbits,
                      const unsigned int* __restrict__ rowor,
                      Acc* __restrict__ acc) {
    __shared__ unsigned int eM[32], eE[32];
    __shared__ float redf[12];                // 4 waves * 3 sums
    __shared__ unsigned int redc[8];          // 4 waves * 2 counts

    const int t  = threadIdx.x;
    const int Rf = blockIdx.x;                // flat row 0..16383
    const int b  = Rf >> 10;
    const int i  = Rf & 1023;

    unsigned int cM = 0, cE = 0;
    if (t < 32) {
        unsigned int m = maskbits[(long)Rf * WPR + t];
        unsigned int e = 0;
        int lo = i - 7; if (lo < 0) lo = 0;
        int hi = i + 7; if (hi > 1023) hi = 1023;
        const unsigned int* base = rowor + ((long)b << 10) * WPR + t;
        for (int ri = lo; ri <= hi; ++ri) e |= base[(long)ri * WPR];
        eM[t] = m;  eE[t] = e;
        cM = __popc(m);  cE = __popc(e);
    }
    __syncthreads();

    float sE = 0.f, sB = 0.f, sT = 0.f;
    const float* prow = pred + (long)Rf * IMG_W;
    #pragma unroll
    for (int k = 0; k < 4; ++k) {
        int p = t + k * 256;
        float pv = prow[p];
        unsigned int m = (eM[p >> 5] >> (p & 31)) & 1u;
        unsigned int e = (eE[p >> 5] >> (p & 31)) & 1u;
        float bce = m ? -logf(pv) : -log1pf(-pv);
        sE += m ? bce : 0.f;
        sB += (e & ~m & 1u) ? bce : 0.f;
        sT += e ? 0.f : bce;
    }

    // wave (64-lane) shuffle reduction
    #pragma unroll
    for (int off = 32; off; off >>= 1) {
        sE += __shfl_down(sE, off);
        sB += __shfl_down(sB, off);
        sT += __shfl_down(sT, off);
        cM += __shfl_down(cM, off);
        cE += __shfl_down(cE, off);
    }
    const int wave = t >> 6, lane = t & 63;
    if (lane == 0) {
        redf[wave * 3 + 0] = sE;
        redf[wave * 3 + 1] = sB;
        redf[wave * 3 + 2] = sT;
        redc[wave * 2 + 0] = cM;
        redc[wave * 2 + 1] = cE;
    }
    __syncthreads();
    if (t == 0) {
        float tE = 0.f, tB = 0.f, tT = 0.f;
        unsigned int tM = 0, tEd = 0;
        #pragma unroll
        for (int wv = 0; wv < 4; ++wv) {
            tE += redf[wv * 3 + 0];
            tB += redf[wv * 3 + 1];
            tT += redf[wv * 3 + 2];
            tM  += redc[wv * 2 + 0];
            tEd += redc[wv * 2 + 1];
        }
        atomicAdd(&acc->sE, (double)tE);
        atomicAdd(&acc->sB, (double)tB);
        atomicAdd(&acc->sT, (double)tT);
        atomicAdd(&acc->cMask, tM);
        atomicAdd(&acc->cEdge, tEd);
    }
}

// ---------------- Kernel 3: finalize scalar ---------------------------------
__global__ void k_final(const Acc* __restrict__ acc, float* __restrict__ out) {
    double nE    = (double)acc->cMask;
    double nEdge = (double)acc->cEdge;
    double nBnd  = nEdge - nE;
    double nT    = NTOTAL - nEdge;
    double wE = (1.0 - nE   / NTOTAL) * 1.0;
    double wB = (1.0 - nBnd / NTOTAL) * 0.8;
    double wT = (1.0 - nT   / NTOTAL) * 0.5;
    double loss = (wE * acc->sE + wB * acc->sB + wT * acc->sT) / NTOTAL;
    out[0] = (float)loss;
}

extern "C" void kernel_launch(void* const* d_in, const int* in_sizes, int n_in,
                              void* d_out, int out_size, void* d_ws, size_t ws_size,
                              hipStream_t stream) {
    const float* pred  = (const float*)d_in[0];   // Pred, float32, 16*1*1024*1024
    const int*   label = (const int*)d_in[1];     // label, int32, same shape
    float* out = (float*)d_out;

    char* ws = (char*)d_ws;
    Acc* acc = (Acc*)ws;                                       // 64 B
    unsigned int* maskbits = (unsigned int*)(ws + 256);        // 2 MB
    unsigned int* rowor    = (unsigned int*)(ws + 256 + (size_t)NROWS * WPR * 4); // 2 MB

    hipMemsetAsync(acc, 0, sizeof(Acc), stream);
    k_dilate_h<<<NROWS / 8, 256, 0, stream>>>(label, maskbits, rowor);
    k_bce<<<NROWS, 256, 0, stream>>>(pred, maskbits, rowor, acc);
    k_final<<<1, 1, 0, stream>>>(acc, out);
}

// Round 2
// 173.950 us; speedup vs baseline: 6.3491x; 6.3491x over previous
//
#include <hip/hip_runtime.h>
#include <math.h>

// Problem constants (from reference setup_inputs): B=16, C=1, H=1024, W=1024
#define IMG_H 1024
#define IMG_W 1024
#define NB    16
#define NROWS (NB * IMG_H)        // 16384 flat rows
#define WPR   (IMG_W / 32)        // 32 u32 words per row
#define NTOTAL 16777216.0
#define NBUCKET 1024

struct Acc {
    double sE, sB, sT;            // bce partial sums per class
    unsigned int cMask, cEdge;    // counts of label==1 and edge==1
};                                 // 32 bytes

// ---------------- Kernel 1: bitpack label + horizontal 15-tap OR dilation ---
// Each block: 8 consecutive flat rows (8192 pixels), 256 threads.
__global__ void k_dilate_h(const int* __restrict__ label,
                           unsigned int* __restrict__ maskbits,
                           unsigned int* __restrict__ rowor) {
    __shared__ unsigned int lm[256];          // 8 rows * 32 words
    const int t = threadIdx.x;
    const int wave = t >> 6, lane = t & 63;
    const long rowBase = (long)blockIdx.x * 8;
    const long pixBase = rowBase * IMG_W;

    #pragma unroll 4
    for (int it = 0; it < 32; ++it) {
        int idx = it * 256 + t;               // 0..8191 within block tile
        int lab = label[pixBase + idx];
        unsigned long long bal = __ballot(lab != 0);
        if (lane == 0) {
            int wi = (it * 256 + wave * 64) >> 5;
            lm[wi]     = (unsigned int)bal;
            lm[wi + 1] = (unsigned int)(bal >> 32);
        }
    }
    __syncthreads();

    // One output word per thread: OR of bits within +/-7 of each bit position.
    const int wd = t & 31;
    unsigned int prev = wd        ? lm[t - 1] : 0u;
    unsigned int cur  =             lm[t];
    unsigned int next = (wd < 31) ? lm[t + 1] : 0u;
    // 64-bit window = bits 16..79 of the 96-bit (prev,cur,next) row segment
    unsigned long long Wn = (((unsigned long long)prev) >> 16)
                          | (((unsigned long long)cur)  << 16)
                          | (((unsigned long long)next) << 48);
    unsigned long long acc = Wn;
    #pragma unroll
    for (int d = 1; d <= 7; ++d) acc |= (Wn >> d) | (Wn << d);

    long o = rowBase * WPR + t;               // coalesced word writes
    maskbits[o] = cur;
    rowor[o]    = (unsigned int)(acc >> 16);
}

// ---------------- Kernel 2: vertical OR + classified BCE + reduction --------
// One block per flat row, 256 threads, float4 per thread (coalesced).
__global__ void k_bce(const float* __restrict__ pred,
                      const unsigned int* __restrict__ maskbits,
                      const unsigned int* __restrict__ rowor,
                      Acc* __restrict__ acc) {
    __shared__ unsigned int eM[32], eE[32];
    __shared__ float redf[12];                // 4 waves * 3 sums
    __shared__ unsigned int redc[8];          // 4 waves * 2 counts

    const int t  = threadIdx.x;
    const int Rf = blockIdx.x;                // flat row 0..16383
    const int b  = Rf >> 10;
    const int i  = Rf & 1023;

    if (t < 32) { eE[t] = 0u; eM[t] = maskbits[(long)Rf * WPR + t]; }
    __syncthreads();

    // Vertical 15-tap OR, 4-way parallel per word (threads 0..127)
    if (t < 128) {
        const int w = t & 31, g = t >> 5;     // word, group 0..3
        int lo = i - 7; if (lo < 0) lo = 0;
        int hi = i + 7; if (hi > 1023) hi = 1023;
        unsigned int e = 0u;
        const unsigned int* base = rowor + ((long)b << 10) * WPR + w;
        for (int ri = lo + g; ri <= hi; ri += 4) e |= base[(long)ri * WPR];
        atomicOr(&eE[w], e);
    }
    __syncthreads();

    // 4 pixels per thread via one float4 load; class bits from a nibble.
    float sE = 0.f, sB = 0.f, sT = 0.f;
    unsigned int cM = 0, cE = 0;
    const float4 pv = ((const float4*)(pred + (long)Rf * IMG_W))[t];
    const unsigned int sh = (t & 7) << 2;
    const unsigned int mN = (eM[t >> 3] >> sh) & 0xFu;
    const unsigned int eN = (eE[t >> 3] >> sh) & 0xFu;
    const float pj[4] = {pv.x, pv.y, pv.z, pv.w};
    #pragma unroll
    for (int j = 0; j < 4; ++j) {
        unsigned int m = (mN >> j) & 1u;
        unsigned int e = (eN >> j) & 1u;
        float bce = m ? -__logf(pj[j]) : -__logf(1.0f - pj[j]);
        sE += m ? bce : 0.f;
        sB += (e & ~m & 1u) ? bce : 0.f;
        sT += e ? 0.f : bce;
        cM += m;  cE += e;
    }

    // wave (64-lane) shuffle reduction
    #pragma unroll
    for (int off = 32; off; off >>= 1) {
        sE += __shfl_down(sE, off);
        sB += __shfl_down(sB, off);
        sT += __shfl_down(sT, off);
        cM += __shfl_down(cM, off);
        cE += __shfl_down(cE, off);
    }
    const int wave = t >> 6, lane = t & 63;
    if (lane == 0) {
        redf[wave * 3 + 0] = sE;
        redf[wave * 3 + 1] = sB;
        redf[wave * 3 + 2] = sT;
        redc[wave * 2 + 0] = cM;
        redc[wave * 2 + 1] = cE;
    }
    __syncthreads();
    if (t == 0) {
        float tE = 0.f, tB = 0.f, tT = 0.f;
        unsigned int tM = 0, tEd = 0;
        #pragma unroll
        for (int wv = 0; wv < 4; ++wv) {
            tE += redf[wv * 3 + 0];
            tB += redf[wv * 3 + 1];
            tT += redf[wv * 3 + 2];
            tM  += redc[wv * 2 + 0];
            tEd += redc[wv * 2 + 1];
        }
        Acc* a = &acc[Rf & (NBUCKET - 1)];    // scatter: <=16 blocks/bucket
        atomicAdd(&a->sE, (double)tE);
        atomicAdd(&a->sB, (double)tB);
        atomicAdd(&a->sT, (double)tT);
        atomicAdd(&a->cMask, tM);
        atomicAdd(&a->cEdge, tEd);
    }
}

// ---------------- Kernel 3: reduce buckets + finalize scalar ----------------
__global__ void k_final(const Acc* __restrict__ acc, float* __restrict__ out) {
    __shared__ double redd[12];               // 4 waves * 3
    __shared__ double redn[8];                // 4 waves * 2 (counts as double)
    const int t = threadIdx.x;                // 256 threads
    double sE = 0.0, sB = 0.0, sT = 0.0, nM = 0.0, nEd = 0.0;
    for (int idx = t; idx < NBUCKET; idx += 256) {
        sE += acc[idx].sE;  sB += acc[idx].sB;  sT += acc[idx].sT;
        nM += (double)acc[idx].cMask;  nEd += (double)acc[idx].cEdge;
    }
    #pragma unroll
    for (int off = 32; off; off >>= 1) {
        sE += __shfl_down(sE, off);
        sB += __shfl_down(sB, off);
        sT += __shfl_down(sT, off);
        nM += __shfl_down(nM, off);
        nEd += __shfl_down(nEd, off);
    }
    const int wave = t >> 6, lane = t & 63;
    if (lane == 0) {
        redd[wave * 3 + 0] = sE;
        redd[wave * 3 + 1] = sB;
        redd[wave * 3 + 2] = sT;
        redn[wave * 2 + 0] = nM;
        redn[wave * 2 + 1] = nEd;
    }
    __syncthreads();
    if (t == 0) {
        double tE = 0, tB = 0, tT = 0, tM = 0, tEd = 0;
        #pragma unroll
        for (int wv = 0; wv < 4; ++wv) {
            tE += redd[wv * 3 + 0];
            tB += redd[wv * 3 + 1];
            tT += redd[wv * 3 + 2];
            tM  += redn[wv * 2 + 0];
            tEd += redn[wv * 2 + 1];
        }
        double nBnd = tEd - tM;
        double nT   = NTOTAL - tEd;
        double wE = (1.0 - tM   / NTOTAL) * 1.0;
        double wB = (1.0 - nBnd / NTOTAL) * 0.8;
        double wT = (1.0 - nT   / NTOTAL) * 0.5;
        out[0] = (float)((wE * tE + wB * tB + wT * tT) / NTOTAL);
    }
}

extern "C" void kernel_launch(void* const* d_in, const int* in_sizes, int n_in,
                              void* d_out, int out_size, void* d_ws, size_t ws_size,
                              hipStream_t stream) {
    const float* pred  = (const float*)d_in[0];   // Pred, float32, 16*1*1024*1024
    const int*   label = (const int*)d_in[1];     // label, int32, same shape
    float* out = (float*)d_out;

    char* ws = (char*)d_ws;
    Acc* acc = (Acc*)ws;                                        // 32 KB buckets
    unsigned int* maskbits = (unsigned int*)(ws + (size_t)NBUCKET * sizeof(Acc));
    unsigned int* rowor    = (unsigned int*)(ws + (size_t)NBUCKET * sizeof(Acc)
                                               + (size_t)NROWS * WPR * 4);

    hipMemsetAsync(acc, 0, (size_t)NBUCKET * sizeof(Acc), stream);
    k_dilate_h<<<NROWS / 8, 256, 0, stream>>>(label, maskbits, rowor);
    k_bce<<<NROWS, 256, 0, stream>>>(pred, maskbits, rowor, acc);
    k_final<<<1, 256, 0, stream>>>(acc, out);
}

// Round 3
// 162.027 us; speedup vs baseline: 6.8163x; 1.0736x over previous
//
#include <hip/hip_runtime.h>
#include <math.h>

// Problem constants (from reference setup_inputs): B=16, C=1, H=1024, W=1024
#define IMG_H 1024
#define IMG_W 1024
#define NB    16
#define NROWS (NB * IMG_H)        // 16384 flat rows
#define WPR   (IMG_W / 32)        // 32 u32 words per row
#define NTOTAL 16777216.0
#define NBUCKET 1024
#define LN2 0.6931471805599453

struct Acc {
    double s2A, s2E, s2M;         // sums of log2(pSel) over: all px, edge px, mask px
    unsigned int cMask, cEdge;    // counts of label==1 and edge==1
};

// ---------------- Kernel 1: bitpack label + horizontal 15-tap OR dilation ---
// Each block: 8 consecutive flat rows (8192 pixels), 256 threads.
__global__ void k_dilate_h(const int* __restrict__ label,
                           unsigned int* __restrict__ maskbits,
                           unsigned int* __restrict__ rowor) {
    __shared__ unsigned int lm[256];          // 8 rows * 32 words
    const int t = threadIdx.x;
    const int wave = t >> 6, lane = t & 63;
    const long rowBase = (long)blockIdx.x * 8;
    const long pixBase = rowBase * IMG_W;

    #pragma unroll 4
    for (int it = 0; it < 32; ++it) {
        int idx = it * 256 + t;               // 0..8191 within block tile
        int lab = label[pixBase + idx];
        unsigned long long bal = __ballot(lab != 0);
        if (lane == 0) {
            int wi = (it * 256 + wave * 64) >> 5;
            lm[wi]     = (unsigned int)bal;
            lm[wi + 1] = (unsigned int)(bal >> 32);
        }
    }
    __syncthreads();

    // One output word per thread: OR of bits within +/-7 of each bit position.
    const int wd = t & 31;
    unsigned int prev = wd        ? lm[t - 1] : 0u;
    unsigned int cur  =             lm[t];
    unsigned int next = (wd < 31) ? lm[t + 1] : 0u;
    unsigned long long Wn = (((unsigned long long)prev) >> 16)
                          | (((unsigned long long)cur)  << 16)
                          | (((unsigned long long)next) << 48);
    unsigned long long acc = Wn;
    #pragma unroll
    for (int d = 1; d <= 7; ++d) acc |= (Wn >> d) | (Wn << d);

    long o = rowBase * WPR + t;               // coalesced word writes
    maskbits[o] = cur;
    rowor[o]    = (unsigned int)(acc >> 16);
}

// ---------------- Kernel 2: vertical OR + classified BCE, 8 rows/block ------
// 2048 blocks x 256 threads; each block = 8 rows (8192 px), 32 px/thread.
__global__ void k_bce(const float* __restrict__ pred,
                      const unsigned int* __restrict__ maskbits,
                      const unsigned int* __restrict__ rowor,
                      Acc* __restrict__ acc) {
    __shared__ unsigned int eM[256], eE[256]; // 8 rows * 32 words each
    __shared__ float redf[12];                // 4 waves * 3 sums
    __shared__ unsigned int redc[8];          // 4 waves * 2 counts

    const int t  = threadIdx.x;
    const int R0 = blockIdx.x * 8;            // first flat row of tile
    const int b  = R0 >> 10;                  // image index
    const int i0 = R0 & 1023;                 // first row within image

    // Vertical 15-tap OR: one edge word per thread. g=row-in-tile, w=word.
    const int g = t >> 5, w = t & 31;
    {
        const int i = i0 + g;
        int lo = i - 7; if (lo < 0) lo = 0;
        int hi = i + 7; if (hi > 1023) hi = 1023;
        const unsigned int* base = rowor + ((long)b << 10) * WPR + w;
        unsigned int e = 0u;
        for (int ri = lo; ri <= hi; ++ri) e |= base[(long)ri * WPR];
        eE[t] = e;
        unsigned int m = maskbits[(long)(R0 + g) * WPR + w];
        eM[t] = m;
    }
    unsigned int cM = __popc(eM[t]), cE = __popc(eE[t]);
    __syncthreads();

    // 32 px/thread via 8 coalesced float4 loads; accumulate log2 sums.
    float s2A = 0.f, s2E = 0.f, s2M = 0.f;
    const float4* p4 = (const float4*)(pred + (long)R0 * IMG_W);
    #pragma unroll
    for (int k = 0; k < 8; ++k) {
        const int f = t + k * 256;            // float4 index in tile, 0..2047
        const float4 pv = p4[f];
        const unsigned int sh = (f & 7) << 2;
        const unsigned int mN = (eM[f >> 3] >> sh) & 0xFu;
        const unsigned int eN = (eE[f >> 3] >> sh) & 0xFu;
        const float pj[4] = {pv.x, pv.y, pv.z, pv.w};
        #pragma unroll
        for (int j = 0; j < 4; ++j) {
            const unsigned int m = (mN >> j) & 1u;
            const unsigned int e = (eN >> j) & 1u;
            const float x = m ? pj[j] : 1.0f - pj[j];
            const float l = __log2f(x);
            s2A += l;
            s2E += e ? l : 0.f;
            s2M += m ? l : 0.f;
        }
    }

    // wave (64-lane) shuffle reduction
    #pragma unroll
    for (int off = 32; off; off >>= 1) {
        s2A += __shfl_down(s2A, off);
        s2E += __shfl_down(s2E, off);
        s2M += __shfl_down(s2M, off);
        cM  += __shfl_down(cM, off);
        cE  += __shfl_down(cE, off);
    }
    const int wave = t >> 6, lane = t & 63;
    if (lane == 0) {
        redf[wave * 3 + 0] = s2A;
        redf[wave * 3 + 1] = s2E;
        redf[wave * 3 + 2] = s2M;
        redc[wave * 2 + 0] = cM;
        redc[wave * 2 + 1] = cE;
    }
    __syncthreads();
    if (t == 0) {
        float tA = 0.f, tEg = 0.f, tMg = 0.f;
        unsigned int tM = 0, tEd = 0;
        #pragma unroll
        for (int wv = 0; wv < 4; ++wv) {
            tA  += redf[wv * 3 + 0];
            tEg += redf[wv * 3 + 1];
            tMg += redf[wv * 3 + 2];
            tM  += redc[wv * 2 + 0];
            tEd += redc[wv * 2 + 1];
        }
        Acc* a = &acc[blockIdx.x & (NBUCKET - 1)];   // 2 blocks/bucket
        atomicAdd(&a->s2A, (double)tA);
        atomicAdd(&a->s2E, (double)tEg);
        atomicAdd(&a->s2M, (double)tMg);
        atomicAdd(&a->cMask, tM);
        atomicAdd(&a->cEdge, tEd);
    }
}

// ---------------- Kernel 3: reduce buckets + finalize scalar ----------------
__global__ void k_final(const Acc* __restrict__ acc, float* __restrict__ out) {
    __shared__ double redd[12];
    __shared__ double redn[8];
    const int t = threadIdx.x;                // 256 threads
    double sA = 0.0, sEg = 0.0, sMg = 0.0, nM = 0.0, nEd = 0.0;
    for (int idx = t; idx < NBUCKET; idx += 256) {
        sA  += acc[idx].s2A;  sEg += acc[idx].s2E;  sMg += acc[idx].s2M;
        nM  += (double)acc[idx].cMask;  nEd += (double)acc[idx].cEdge;
    }
    #pragma unroll
    for (int off = 32; off; off >>= 1) {
        sA  += __shfl_down(sA, off);
        sEg += __shfl_down(sEg, off);
        sMg += __shfl_down(sMg, off);
        nM  += __shfl_down(nM, off);
        nEd += __shfl_down(nEd, off);
    }
    const int wave = t >> 6, lane = t & 63;
    if (lane == 0) {
        redd[wave * 3 + 0] = sA;
        redd[wave * 3 + 1] = sEg;
        redd[wave * 3 + 2] = sMg;
        redn[wave * 2 + 0] = nM;
        redn[wave * 2 + 1] = nEd;
    }
    __syncthreads();
    if (t == 0) {
        double tA = 0, tEg = 0, tMg = 0, tM = 0, tEd = 0;
        #pragma unroll
        for (int wv = 0; wv < 4; ++wv) {
            tA  += redd[wv * 3 + 0];
            tEg += redd[wv * 3 + 1];
            tMg += redd[wv * 3 + 2];
            tM  += redn[wv * 2 + 0];
            tEd += redn[wv * 2 + 1];
        }
        // bce sums per class (log2 -> natural log, negate)
        double sE_bce = -LN2 * tMg;           // label==1 pixels
        double sEdge  = -LN2 * tEg;           // edge==1 pixels
        double sAll   = -LN2 * tA;            // all pixels
        double sB_bce = sEdge - sE_bce;       // boundary band
        double sT_bce = sAll - sEdge;         // texture
        double nBnd = tEd - tM;
        double nT   = NTOTAL - tEd;
        double wE = (1.0 - tM   / NTOTAL) * 1.0;
        double wB = (1.0 - nBnd / NTOTAL) * 0.8;
        double wT = (1.0 - nT   / NTOTAL) * 0.5;
        out[0] = (float)((wE * sE_bce + wB * sB_bce + wT * sT_bce) / NTOTAL);
    }
}

extern "C" void kernel_launch(void* const* d_in, const int* in_sizes, int n_in,
                              void* d_out, int out_size, void* d_ws, size_t ws_size,
                              hipStream_t stream) {
    const float* pred  = (const float*)d_in[0];   // Pred, float32
    const int*   label = (const int*)d_in[1];     // label, int32
    float* out = (float*)d_out;

    char* ws = (char*)d_ws;
    Acc* acc = (Acc*)ws;
    unsigned int* maskbits = (unsigned int*)(ws + (size_t)NBUCKET * sizeof(Acc));
    unsigned int* rowor    = (unsigned int*)(ws + (size_t)NBUCKET * sizeof(Acc)
                                               + (size_t)NROWS * WPR * 4);

    hipMemsetAsync(acc, 0, (size_t)NBUCKET * sizeof(Acc), stream);
    k_dilate_h<<<NROWS / 8, 256, 0, stream>>>(label, maskbits, rowor);
    k_bce<<<NROWS / 8, 256, 0, stream>>>(pred, maskbits, rowor, acc);
    k_final<<<1, 256, 0, stream>>>(acc, out);
}

// Round 4
// 150.951 us; speedup vs baseline: 7.3164x; 1.0734x over previous
//
#include <hip/hip_runtime.h>
#include <math.h>

// Problem constants (from reference setup_inputs): B=16, C=1, H=1024, W=1024
#define IMG_H 1024
#define IMG_W 1024
#define NB    16
#define NROWS (NB * IMG_H)        // 16384 flat rows
#define WPR   (IMG_W / 32)        // 32 u32 words per row
#define NTOTAL 16777216.0
#define NBUCKET 1024
#define LN2 0.6931471805599453

struct Acc {
    double s2A, s2E, s2M;         // sums of log2(pSel) over: all px, edge px, mask px
    unsigned int cMask, cEdge;    // counts of label==1 and edge==1
};                                 // 32 bytes = 8 dwords

// ---------------- Kernel 1: bitpack label + horizontal 15-tap OR dilation ---
// Each block: 8 consecutive flat rows (8192 px), 256 threads, int4 loads.
// Also zeroes the Acc buckets (blocks 0..NBUCKET-1), replacing a memset launch.
__global__ void k_dilate_h(const int* __restrict__ label,
                           unsigned int* __restrict__ maskbits,
                           unsigned int* __restrict__ rowor,
                           Acc* __restrict__ acc) {
    __shared__ unsigned int lm[256];          // 8 rows * 32 words
    const int t = threadIdx.x;
    const long rowBase = (long)blockIdx.x * 8;
    const long pixBase = rowBase * IMG_W;

    if (blockIdx.x < NBUCKET && t < 8)        // zero this block's bucket
        ((unsigned int*)&acc[blockIdx.x])[t] = 0u;

    // Bitpack: each thread loads 8 int4 (32 labels); nibble -> word via 3 shfl_xor.
    const int4* L = (const int4*)(label + pixBase);
    #pragma unroll
    for (int k = 0; k < 8; ++k) {
        const int fi = k * 256 + t;           // int4 index in tile, 0..2047
        const int4 v = L[fi];
        unsigned int wbits = ((unsigned int)(v.x & 1)
                           | ((unsigned int)(v.y & 1) << 1)
                           | ((unsigned int)(v.z & 1) << 2)
                           | ((unsigned int)(v.w & 1) << 3)) << ((t & 7) * 4);
        wbits |= __shfl_xor(wbits, 1);
        wbits |= __shfl_xor(wbits, 2);
        wbits |= __shfl_xor(wbits, 4);
        if ((t & 7) == 0) lm[fi >> 3] = wbits;
    }
    __syncthreads();

    // One output word per thread: OR of bits within +/-7 of each bit position.
    const int wd = t & 31;
    unsigned int prev = wd        ? lm[t - 1] : 0u;
    unsigned int cur  =             lm[t];
    unsigned int next = (wd < 31) ? lm[t + 1] : 0u;
    unsigned long long Wn = (((unsigned long long)prev) >> 16)
                          | (((unsigned long long)cur)  << 16)
                          | (((unsigned long long)next) << 48);
    unsigned long long a = Wn;
    #pragma unroll
    for (int d = 1; d <= 7; ++d) a |= (Wn >> d) | (Wn << d);

    long o = rowBase * WPR + t;               // coalesced word writes
    maskbits[o] = cur;
    rowor[o]    = (unsigned int)(a >> 16);
}

// ---------------- Kernel 2: vertical OR + classified BCE, 8 rows/block ------
// 2048 blocks x 256 threads; each block = 8 rows (8192 px), 32 px/thread.
__global__ void k_bce(const float* __restrict__ pred,
                      const unsigned int* __restrict__ maskbits,
                      const unsigned int* __restrict__ rowor,
                      Acc* __restrict__ acc) {
    __shared__ unsigned int eM[256], eE[256]; // 8 rows * 32 words each
    __shared__ float redf[12];                // 4 waves * 3 sums
    __shared__ unsigned int redc[8];          // 4 waves * 2 counts

    const int t  = threadIdx.x;
    const int R0 = blockIdx.x * 8;            // first flat row of tile
    const int b  = R0 >> 10;                  // image index
    const int i0 = R0 & 1023;                 // first row within image

    // Vertical 15-tap OR: one edge word per thread. g=row-in-tile, w=word.
    const int g = t >> 5, w = t & 31;
    {
        const int i = i0 + g;
        int lo = i - 7; if (lo < 0) lo = 0;
        int hi = i + 7; if (hi > 1023) hi = 1023;
        const unsigned int* base = rowor + ((long)b << 10) * WPR + w;
        unsigned int e = 0u;
        for (int ri = lo; ri <= hi; ++ri) e |= base[(long)ri * WPR];
        eE[t] = e;
        eM[t] = maskbits[(long)(R0 + g) * WPR + w];
    }
    unsigned int cM = __popc(eM[t]), cE = __popc(eE[t]);
    __syncthreads();

    // 32 px/thread via 8 coalesced float4 loads; accumulate log2 sums.
    float s2A = 0.f, s2E = 0.f, s2M = 0.f;
    const float4* p4 = (const float4*)(pred + (long)R0 * IMG_W);
    #pragma unroll
    for (int k = 0; k < 8; ++k) {
        const int f = t + k * 256;            // float4 index in tile, 0..2047
        const float4 pv = p4[f];
        const unsigned int sh = (f & 7) << 2;
        const unsigned int mN = (eM[f >> 3] >> sh) & 0xFu;
        const unsigned int eN = (eE[f >> 3] >> sh) & 0xFu;
        const float pj[4] = {pv.x, pv.y, pv.z, pv.w};
        #pragma unroll
        for (int j = 0; j < 4; ++j) {
            const unsigned int m = (mN >> j) & 1u;
            const unsigned int e = (eN >> j) & 1u;
            const float x = m ? pj[j] : 1.0f - pj[j];
            const float l = __log2f(x);
            s2A += l;
            s2E += e ? l : 0.f;
            s2M += m ? l : 0.f;
        }
    }

    // wave (64-lane) shuffle reduction
    #pragma unroll
    for (int off = 32; off; off >>= 1) {
        s2A += __shfl_down(s2A, off);
        s2E += __shfl_down(s2E, off);
        s2M += __shfl_down(s2M, off);
        cM  += __shfl_down(cM, off);
        cE  += __shfl_down(cE, off);
    }
    const int wave = t >> 6, lane = t & 63;
    if (lane == 0) {
        redf[wave * 3 + 0] = s2A;
        redf[wave * 3 + 1] = s2E;
        redf[wave * 3 + 2] = s2M;
        redc[wave * 2 + 0] = cM;
        redc[wave * 2 + 1] = cE;
    }
    __syncthreads();
    if (t == 0) {
        float tA = 0.f, tEg = 0.f, tMg = 0.f;
        unsigned int tM = 0, tEd = 0;
        #pragma unroll
        for (int wv = 0; wv < 4; ++wv) {
            tA  += redf[wv * 3 + 0];
            tEg += redf[wv * 3 + 1];
            tMg += redf[wv * 3 + 2];
            tM  += redc[wv * 2 + 0];
            tEd += redc[wv * 2 + 1];
        }
        Acc* a = &acc[blockIdx.x & (NBUCKET - 1)];   // 2 blocks/bucket
        atomicAdd(&a->s2A, (double)tA);
        atomicAdd(&a->s2E, (double)tEg);
        atomicAdd(&a->s2M, (double)tMg);
        atomicAdd(&a->cMask, tM);
        atomicAdd(&a->cEdge, tEd);
    }
}

// ---------------- Kernel 3: reduce buckets + finalize scalar ----------------
__global__ void k_final(const Acc* __restrict__ acc, float* __restrict__ out) {
    __shared__ double redd[12];
    __shared__ double redn[8];
    const int t = threadIdx.x;                // 256 threads
    double sA = 0.0, sEg = 0.0, sMg = 0.0, nM = 0.0, nEd = 0.0;
    for (int idx = t; idx < NBUCKET; idx += 256) {
        sA  += acc[idx].s2A;  sEg += acc[idx].s2E;  sMg += acc[idx].s2M;
        nM  += (double)acc[idx].cMask;  nEd += (double)acc[idx].cEdge;
    }
    #pragma unroll
    for (int off = 32; off; off >>= 1) {
        sA  += __shfl_down(sA, off);
        sEg += __shfl_down(sEg, off);
        sMg += __shfl_down(sMg, off);
        nM  += __shfl_down(nM, off);
        nEd += __shfl_down(nEd, off);
    }
    const int wave = t >> 6, lane = t & 63;
    if (lane == 0) {
        redd[wave * 3 + 0] = sA;
        redd[wave * 3 + 1] = sEg;
        redd[wave * 3 + 2] = sMg;
        redn[wave * 2 + 0] = nM;
        redn[wave * 2 + 1] = nEd;
    }
    __syncthreads();
    if (t == 0) {
        double tA = 0, tEg = 0, tMg = 0, tM = 0, tEd = 0;
        #pragma unroll
        for (int wv = 0; wv < 4; ++wv) {
            tA  += redd[wv * 3 + 0];
            tEg += redd[wv * 3 + 1];
            tMg += redd[wv * 3 + 2];
            tM  += redn[wv * 2 + 0];
            tEd += redn[wv * 2 + 1];
        }
        double sE_bce = -LN2 * tMg;           // label==1 pixels
        double sEdge  = -LN2 * tEg;           // edge==1 pixels
        double sAll   = -LN2 * tA;            // all pixels
        double sB_bce = sEdge - sE_bce;       // boundary band
        double sT_bce = sAll - sEdge;         // texture
        double nBnd = tEd - tM;
        double nT   = NTOTAL - tEd;
        double wE = (1.0 - tM   / NTOTAL) * 1.0;
        double wB = (1.0 - nBnd / NTOTAL) * 0.8;
        double wT = (1.0 - nT   / NTOTAL) * 0.5;
        out[0] = (float)((wE * sE_bce + wB * sB_bce + wT * sT_bce) / NTOTAL);
    }
}

extern "C" void kernel_launch(void* const* d_in, const int* in_sizes, int n_in,
                              void* d_out, int out_size, void* d_ws, size_t ws_size,
                              hipStream_t stream) {
    const float* pred  = (const float*)d_in[0];   // Pred, float32
    const int*   label = (const int*)d_in[1];     // label, int32
    float* out = (float*)d_out;

    char* ws = (char*)d_ws;
    Acc* acc = (Acc*)ws;
    unsigned int* maskbits = (unsigned int*)(ws + (size_t)NBUCKET * sizeof(Acc));
    unsigned int* rowor    = (unsigned int*)(ws + (size_t)NBUCKET * sizeof(Acc)
                                               + (size_t)NROWS * WPR * 4);

    k_dilate_h<<<NROWS / 8, 256, 0, stream>>>(label, maskbits, rowor, acc);
    k_bce<<<NROWS / 8, 256, 0, stream>>>(pred, maskbits, rowor, acc);
    k_final<<<1, 256, 0, stream>>>(acc, out);
}